// Round 10
// baseline (147.475 us; speedup 1.0000x reference)
//
#include <hip/hip_runtime.h>

// RandHashProj: out[b, sel[r]] += sign[r] * x[b, r]
// proj (8192x8192 f32): exactly one +-1 per row; per-column count ~ Poisson(1).
// R10: width-4 ELL in registers + zero-slot branchless decode; PERSISTENT
// gather (1 block/CU), 2-row f32 groups double-buffered via async
// __builtin_amdgcn_global_load_lds (16B DMA, no VGPR staging, no pack).
// Per group: issue DMA(g+1) -> compute(g) -> one barrier (vmcnt drain = gate).
// Overflow (~35 entries) in a separate thread-owns-row kernel: NO atomics.
// ELL entry (ushort): (r<<2)|(sign<<1); empty = 0x8000 -> r=8192 -> zero pad.

#define OUT_FEAT 8192
#define IN_FEAT 8192
#define OUT_SHIFT 13        // log2(OUT_FEAT)
#define EMPTY_PAIR 0x80008000u

#define GBLOCKS 256         // 1 per CU
#define ROWS_PER_BLK 16     // 4096 / 256
#define NGRP 8              // groups of 2 rows
#define BUF_STRIDE 16400    // f32: row0[0..8191] | z[8192..8199] | row1[8200..16391] | z[16392..16399]

#define AS_GLOBAL __attribute__((address_space(1)))
#define AS_LOCAL  __attribute__((address_space(3)))

__device__ __forceinline__ void gload_lds16(const float* g, float* l) {
    __builtin_amdgcn_global_load_lds(
        reinterpret_cast<const AS_GLOBAL unsigned int*>(reinterpret_cast<uintptr_t>(g)),
        reinterpret_cast<AS_LOCAL unsigned int*>(reinterpret_cast<uintptr_t>(l)),
        16, 0, 0);
}

// ---- Kernel 0: init cur/onum/ell (pattern fill; memset can't write 0x8000) ----
__global__ void init_kernel(int* __restrict__ cur, int* __restrict__ onum,
                            unsigned int* __restrict__ ellw) {
    int i = blockIdx.x * blockDim.x + threadIdx.x;
    if (i < OUT_FEAT) {
        cur[i] = 0;
        ellw[2 * i] = EMPTY_PAIR;      // slots 0,1
        ellw[2 * i + 1] = EMPTY_PAIR;  // slots 2,3
    }
    if (i == 0) *onum = 0;
}

// ---- Kernel A: scan proj; fill width-4 ELL + overflow list ----
__global__ void extract_fill(const float4* __restrict__ proj4, int* __restrict__ cur,
                             int* __restrict__ onum, unsigned int* __restrict__ ovals,
                             unsigned short* __restrict__ ell, long n4) {
    long stride = (long)gridDim.x * blockDim.x;
    for (long i = (long)blockIdx.x * blockDim.x + threadIdx.x; i < n4; i += stride) {
        float4 v = proj4[i];
        if (v.x != 0.f || v.y != 0.f || v.z != 0.f || v.w != 0.f) {
            float a[4] = {v.x, v.y, v.z, v.w};
            #pragma unroll
            for (int k = 0; k < 4; ++k) {
                if (a[k] != 0.f) {
                    long idx = i * 4 + k;
                    int r = (int)(idx >> OUT_SHIFT);
                    int c = (int)(idx & (OUT_FEAT - 1));
                    int sg = (a[k] < 0.f) ? 1 : 0;
                    int pos = atomicAdd(&cur[c], 1);
                    if (pos < 4) {
                        ell[c * 4 + pos] = (unsigned short)((r << 2) | (sg << 1));
                    } else {
                        int o = atomicAdd(onum, 1);
                        ovals[o] = ((unsigned int)c << 14) | ((unsigned int)r << 1) | sg;
                    }
                }
            }
        }
    }
}

// one ELL slot -> dual-row fma (branchless; empty -> zero pads at 8192/16392)
#define SLOT(ek)                                                                  \
    {                                                                             \
        unsigned int _e = (ek);                                                   \
        unsigned int _a = _e & 0xFFFCu;                                           \
        float _v0 = *(const float*)(bufc + _a);                                   \
        float _v1 = *(const float*)(bufc + 32800 + _a);                           \
        float _wt = __builtin_bit_cast(float, 0x3F800000u | ((_e << 30) & 0x80000000u)); \
        s0 = fmaf(_wt, _v0, s0);                                                  \
        s1 = fmaf(_wt, _v1, s1);                                                  \
    }

// ---- Kernel B: persistent gather, async DMA double-buffer ----
__global__ void __launch_bounds__(512) gatherp_kernel(const float* __restrict__ x,
        const ushort4* __restrict__ ell4, float* __restrict__ out) {
    __shared__ float xs[2 * BUF_STRIDE];   // 131200 B
    int t = threadIdx.x;
    int lane = t & 63;
    int wv = t >> 6;                        // 8 waves
    int cbase = (wv << 10) | lane;

    // This thread's 16 ELL columns -> registers (independent burst, L2-hot).
    ushort4 ev[16];
    #pragma unroll
    for (int j = 0; j < 16; ++j) ev[j] = ell4[cbase + (j << 6)];

    int b0 = blockIdx.x * ROWS_PER_BLK;

    // Prologue: DMA group 0 into buf0; zero the pad slots of both buffers.
    {
        const float* src = x + (size_t)b0 * IN_FEAT;
        #pragma unroll
        for (int k = 0; k < 4; ++k) {
            int wo = (k << 11) + (wv << 8);               // f32 units
            gload_lds16(src + wo + (lane << 2), xs + wo);
            gload_lds16(src + 8192 + wo + (lane << 2), xs + 8200 + wo);
        }
    }
    if (t < 8) {
        xs[8192 + t] = 0.f;               xs[16392 + t] = 0.f;
        xs[BUF_STRIDE + 8192 + t] = 0.f;  xs[BUF_STRIDE + 16392 + t] = 0.f;
    }
    __syncthreads();   // vmcnt drain: buf0 ready

    #pragma unroll 2
    for (int g = 0; g < NGRP; ++g) {
        // Issue next group's DMA into the other buffer (runs under compute).
        if (g + 1 < NGRP) {
            const float* src = x + (size_t)(b0 + 2 * (g + 1)) * IN_FEAT;
            float* dst = xs + ((g + 1) & 1) * BUF_STRIDE;
            #pragma unroll
            for (int k = 0; k < 4; ++k) {
                int wo = (k << 11) + (wv << 8);
                gload_lds16(src + wo + (lane << 2), dst + wo);
                gload_lds16(src + 8192 + wo + (lane << 2), dst + 8200 + wo);
            }
        }

        // Compute group g from buf[g&1] (pure LDS + fma, exact f32).
        const char* bufc = (const char*)(xs + (g & 1) * BUF_STRIDE);
        float* orow0 = out + (size_t)(b0 + 2 * g) * OUT_FEAT;
        float* orow1 = orow0 + OUT_FEAT;
        #pragma unroll
        for (int j = 0; j < 16; ++j) {
            int c = cbase + (j << 6);
            float s0 = 0.f, s1 = 0.f;
            SLOT(ev[j].x);
            SLOT(ev[j].y);
            SLOT(ev[j].z);
            SLOT(ev[j].w);
            orow0[c] = s0;   // wave-contiguous 256B stores
            orow1[c] = s1;
        }

        __syncthreads();   // drains: g's LDS reads, g's stores, (g+1)'s DMA
    }
}

// ---- Kernel C: overflow (~35 entries). One thread owns one batch row: no atomics. ----
__global__ void overflow_kernel(const float* __restrict__ x,
        const unsigned int* __restrict__ ovals, const int* __restrict__ onum_p,
        float* __restrict__ out, int batch) {
    int b = blockIdx.x * blockDim.x + threadIdx.x;
    if (b >= batch) return;
    int on = *onum_p;
    const float* xrow = x + (size_t)b * IN_FEAT;
    float* orow = out + (size_t)b * OUT_FEAT;
    for (int m = 0; m < on; ++m) {
        unsigned int e = ovals[m];
        int c = (int)(e >> 14);
        int r = (int)((e >> 1) & (IN_FEAT - 1));
        float wt = (e & 1) ? -1.f : 1.f;
        orow[c] += wt * xrow[r];   // exclusive row ownership -> plain RMW
    }
}

extern "C" void kernel_launch(void* const* d_in, const int* in_sizes, int n_in,
                              void* d_out, int out_size, void* d_ws, size_t ws_size,
                              hipStream_t stream) {
    const float* x = (const float*)d_in[0];
    const float* proj = (const float*)d_in[1];
    float* out = (float*)d_out;

    const int out_feat = OUT_FEAT;
    long proj_elems = (long)in_sizes[1];
    int in_feat = (int)(proj_elems / out_feat);   // 8192
    int batch = in_sizes[0] / in_feat;            // 4096

    // ws layout: [cur 32 KiB][onum 4 B][pad 60 B][ell 64 KiB][ovals 32 KiB]
    char* w = (char*)d_ws;
    int* cur = (int*)w;
    int* onum = (int*)(w + 32 * 1024);
    unsigned int* ellw = (unsigned int*)(w + 32 * 1024 + 64);
    unsigned int* ovals = (unsigned int*)(w + 96 * 1024 + 64);

    init_kernel<<<OUT_FEAT / 256, 256, 0, stream>>>(cur, onum, ellw);
    long n4 = proj_elems / 4;
    extract_fill<<<8192, 256, 0, stream>>>((const float4*)proj, cur, onum, ovals,
                                           (unsigned short*)ellw, n4);
    gatherp_kernel<<<GBLOCKS, 512, 0, stream>>>(x, (const ushort4*)ellw, out);
    overflow_kernel<<<(batch + 255) / 256, 256, 0, stream>>>(x, ovals, onum, out, batch);
}

// Round 11
// 103.692 us; speedup vs baseline: 1.4222x; 1.4222x over previous
//
#include <hip/hip_runtime.h>

// RandHashProj: out[b, sel[r]] += sign[r] * x[b, r]
// proj (8192x8192 f32): exactly ONE +-1 per row; per-column count ~ Poisson(1).
// R11: (a) EARLY-EXIT extract: wave-per-row scan with depth-2 prefetch and
// __ballot exit -> reads ~55% of proj instead of 100%. (b) R8 gather with
// 4-consecutive-columns-per-thread: float4 out stores + 16B ELL reg loads.
// ELL entry (ushort): (r<<2)|(sign<<1); empty = 0x8000 (r=8192 -> zero slot).

#define OUT_FEAT 8192
#define IN_FEAT 8192
#define EMPTY_PAIR 0x80008000u

// ---- Kernel 0: init cur/onum/ell (pattern fill; memset can't write 0x8000) ----
__global__ void init_kernel(int* __restrict__ cur, int* __restrict__ onum,
                            unsigned int* __restrict__ ellw) {
    int i = blockIdx.x * blockDim.x + threadIdx.x;
    if (i < OUT_FEAT) {
        cur[i] = 0;
        ellw[2 * i] = EMPTY_PAIR;      // slots 0,1
        ellw[2 * i + 1] = EMPTY_PAIR;  // slots 2,3
    }
    if (i == 0) *onum = 0;
}

// ---- Kernel A: wave-per-row early-exit scan of proj ----
// Each row has exactly one nonzero; stop at the chunk containing it.
__global__ void __launch_bounds__(256) extract_fill(const float4* __restrict__ proj4,
        int* __restrict__ cur, int* __restrict__ onum,
        unsigned int* __restrict__ ovals, unsigned short* __restrict__ ell) {
    int row = (blockIdx.x << 2) + (threadIdx.x >> 6);   // wave-per-row
    int lane = threadIdx.x & 63;
    const float4* rp = proj4 + (size_t)row * (IN_FEAT / 4) + lane;

    float4 v = rp[0];                     // chunk 0 (wave reads 1 KiB)
    #pragma unroll 1
    for (int k = 0; k < 32; ++k) {
        float4 vn;
        if (k + 1 < 32) vn = rp[(size_t)(k + 1) * 64];   // depth-2 prefetch
        bool hit = (v.x != 0.f) || (v.y != 0.f) || (v.z != 0.f) || (v.w != 0.f);
        if (__ballot(hit)) {              // wave-uniform -> no divergence
            if (hit) {                    // exactly one lane, one component
                int comp; float a;
                if      (v.x != 0.f) { comp = 0; a = v.x; }
                else if (v.y != 0.f) { comp = 1; a = v.y; }
                else if (v.z != 0.f) { comp = 2; a = v.z; }
                else                 { comp = 3; a = v.w; }
                int c = (k << 8) + (lane << 2) + comp;    // column in row
                int sg = (a < 0.f) ? 1 : 0;
                int pos = atomicAdd(&cur[c], 1);
                if (pos < 4) {
                    ell[c * 4 + pos] = (unsigned short)((row << 2) | (sg << 1));
                } else {
                    int o = atomicAdd(onum, 1);
                    ovals[o] = ((unsigned int)c << 14) | ((unsigned int)row << 1) | sg;
                }
            }
            break;
        }
        v = vn;
    }
}

__device__ __forceinline__ unsigned int pack_bf16(float a, float b) {
    unsigned int ua = __builtin_bit_cast(unsigned int, a);
    unsigned int ub = __builtin_bit_cast(unsigned int, b);
    ua = (ua + 0x8000u) >> 16;
    ub = (ub + 0x8000u) & 0xFFFF0000u;
    return ub | ua;
}

// one ELL slot -> fma into s0/s1 (branchless; empty hits xs[8192]=0)
#define SLOT(ek)                                                                 \
    {                                                                            \
        unsigned int _e = (ek);                                                  \
        unsigned int _u = *(const unsigned int*)((const char*)xs + (_e & 0xFFFCu)); \
        float _wt = __builtin_bit_cast(float, 0x3F800000u | ((_e << 30) & 0x80000000u)); \
        s0 = fmaf(_wt, __builtin_bit_cast(float, _u << 16), s0);                 \
        s1 = fmaf(_wt, __builtin_bit_cast(float, _u & 0xFFFF0000u), s1);         \
    }

// one column (two packed slot-words) -> its two row sums
#define COL(u01, u23, dA, dB)                                                    \
    {                                                                            \
        float s0 = 0.f, s1 = 0.f;                                                \
        SLOT((u01) & 0xFFFFu);                                                   \
        SLOT((u01) >> 16);                                                       \
        SLOT((u23) & 0xFFFFu);                                                   \
        SLOT((u23) >> 16);                                                       \
        dA = s0; dB = s1;                                                        \
    }

// ---- Kernel B: gather, 2 rows/block, bf16-packed LDS, ELL in registers,
//      4 consecutive columns per thread -> float4 stores ----
__global__ void __launch_bounds__(512, 4) gather2_kernel(const float4* __restrict__ x4,
        const unsigned short* __restrict__ ell, const unsigned int* __restrict__ ovals,
        const int* __restrict__ onum_p, float* __restrict__ out) {
    __shared__ unsigned int xs[IN_FEAT + 16];  // + zero slot at [IN_FEAT]
    int t = threadIdx.x;
    int lane = t & 63;
    int wv = t >> 6;                 // 8 waves

    // This thread's 4 column-groups (4 consecutive cols each) -> registers.
    // Group g base: c0 = wv*1024 + g*256 + lane*4 ; 32 B of ELL per group.
    uint4 ea[4], eb[4];
    #pragma unroll
    for (int g = 0; g < 4; ++g) {
        int c0 = (wv << 10) + (g << 8) + (lane << 2);
        const uint4* p = (const uint4*)(ell + (size_t)c0 * 4);
        ea[g] = p[0];                // cols c0, c0+1 (slots 01,23 each)
        eb[g] = p[1];                // cols c0+2, c0+3
    }

    int b0 = blockIdx.x * 2;
    const float4* xr0 = x4 + (size_t)b0 * (IN_FEAT / 4);
    const float4* xr1 = xr0 + (IN_FEAT / 4);
    #pragma unroll
    for (int i = 0; i < 4; ++i) {
        int idx = (i << 9) | t;
        float4 a = xr0[idx];
        float4 b = xr1[idx];
        uint4 p;
        p.x = pack_bf16(a.x, b.x);
        p.y = pack_bf16(a.y, b.y);
        p.z = pack_bf16(a.z, b.z);
        p.w = pack_bf16(a.w, b.w);
        ((uint4*)xs)[idx] = p;
    }
    if (t == 0) xs[IN_FEAT] = 0u;    // zero slot for empty entries
    __syncthreads();

    float* orow0 = out + (size_t)b0 * OUT_FEAT;
    float* orow1 = orow0 + OUT_FEAT;

    #pragma unroll
    for (int g = 0; g < 4; ++g) {
        int c0 = (wv << 10) + (g << 8) + (lane << 2);
        float4 o0, o1;
        COL(ea[g].x, ea[g].y, o0.x, o1.x);
        COL(ea[g].z, ea[g].w, o0.y, o1.y);
        COL(eb[g].x, eb[g].y, o0.z, o1.z);
        COL(eb[g].z, eb[g].w, o0.w, o1.w);
        *(float4*)(orow0 + c0) = o0;   // wave stores 1 KiB contiguous
        *(float4*)(orow1 + c0) = o1;
    }

    // Overflow (~35 entries total). Barrier drains plain stores first.
    __syncthreads();
    int on = *onum_p;
    for (int m = t; m < on; m += 512) {
        unsigned int e = ovals[m];
        int c = (int)(e >> 14);
        int r = (int)((e >> 1) & (IN_FEAT - 1));
        float wt = (e & 1) ? -1.f : 1.f;
        unsigned int u = xs[r];
        atomicAdd(&orow0[c], wt * __builtin_bit_cast(float, u << 16));
        atomicAdd(&orow1[c], wt * __builtin_bit_cast(float, u & 0xFFFF0000u));
    }
}

extern "C" void kernel_launch(void* const* d_in, const int* in_sizes, int n_in,
                              void* d_out, int out_size, void* d_ws, size_t ws_size,
                              hipStream_t stream) {
    const float* x = (const float*)d_in[0];
    const float* proj = (const float*)d_in[1];
    float* out = (float*)d_out;

    const int out_feat = OUT_FEAT;
    long proj_elems = (long)in_sizes[1];
    int in_feat = (int)(proj_elems / out_feat);   // 8192
    int batch = in_sizes[0] / in_feat;            // 4096

    // ws layout: [cur 32 KiB][onum 4 B][pad 60 B][ell 64 KiB][ovals 32 KiB]
    char* w = (char*)d_ws;
    int* cur = (int*)w;
    int* onum = (int*)(w + 32 * 1024);
    unsigned int* ellw = (unsigned int*)(w + 32 * 1024 + 64);
    unsigned int* ovals = (unsigned int*)(w + 96 * 1024 + 64);

    init_kernel<<<OUT_FEAT / 256, 256, 0, stream>>>(cur, onum, ellw);
    extract_fill<<<IN_FEAT / 4, 256, 0, stream>>>((const float4*)proj, cur, onum,
                                                  ovals, (unsigned short*)ellw);
    gather2_kernel<<<batch / 2, 512, 0, stream>>>((const float4*)x,
                                                  (const unsigned short*)ellw,
                                                  ovals, onum, out);
}